// Round 1
// baseline (133.123 us; speedup 1.0000x reference)
//
#include <hip/hip_runtime.h>

typedef unsigned short u16;

// ---------- complex helpers ----------
__device__ __forceinline__ float2 cmul(float2 a, float2 b){
  return make_float2(a.x*b.x - a.y*b.y, a.x*b.y + a.y*b.x);
}
__device__ __forceinline__ float2 cmad(float2 acc, float2 a, float2 b){
  acc.x += a.x*b.x - a.y*b.y;
  acc.y += a.x*b.y + a.y*b.x;
  return acc;
}

struct M2 { float2 m[4]; };   // row-major 2x2 complex
struct M4 { float2 m[16]; };  // row-major 4x4 complex

__device__ M2 mul2(const M2 A, const M2 B){
  M2 C;
  #pragma unroll
  for (int r=0;r<2;r++)
    #pragma unroll
    for (int c=0;c<2;c++){
      float2 v = cmul(A.m[2*r+0], B.m[0+c]);
      v = cmad(v, A.m[2*r+1], B.m[2+c]);
      C.m[2*r+c] = v;
    }
  return C;
}
__device__ M4 mul4(const M4 A, const M4 B){
  M4 C;
  #pragma unroll
  for (int r=0;r<4;r++)
    #pragma unroll
    for (int c=0;c<4;c++){
      float2 v = cmul(A.m[4*r+0], B.m[0+c]);
      v = cmad(v, A.m[4*r+1], B.m[4+c]);
      v = cmad(v, A.m[4*r+2], B.m[8+c]);
      v = cmad(v, A.m[4*r+3], B.m[12+c]);
      C.m[4*r+c] = v;
    }
  return C;
}
// kron: A acts on local bit1 (wire a), B on local bit0 (wire b).
// (A kron B)[2ia+ib, 2ja+jb] = A[ia,ja]*B[ib,jb]
__device__ M4 kron(const M2 A, const M2 B){
  M4 M;
  #pragma unroll
  for (int ia=0;ia<2;ia++)
    #pragma unroll
    for (int ib=0;ib<2;ib++)
      #pragma unroll
      for (int ja=0;ja<2;ja++)
        #pragma unroll
        for (int jb=0;jb<2;jb++)
          M.m[(2*ia+ib)*4 + (2*ja+jb)] = cmul(A.m[2*ia+ja], B.m[2*ib+jb]);
  return M;
}
__device__ M2 mRX(float t){ float c=cosf(0.5f*t), s=sinf(0.5f*t); M2 M;
  M.m[0]=make_float2(c,0.f); M.m[1]=make_float2(0.f,-s);
  M.m[2]=make_float2(0.f,-s); M.m[3]=make_float2(c,0.f); return M; }
__device__ M2 mRY(float t){ float c=cosf(0.5f*t), s=sinf(0.5f*t); M2 M;
  M.m[0]=make_float2(c,0.f); M.m[1]=make_float2(-s,0.f);
  M.m[2]=make_float2(s,0.f); M.m[3]=make_float2(c,0.f); return M; }
__device__ M2 mRZ(float t){ float c=cosf(0.5f*t), s=sinf(0.5f*t); M2 M;
  M.m[0]=make_float2(c,-s); M.m[1]=make_float2(0.f,0.f);
  M.m[2]=make_float2(0.f,0.f); M.m[3]=make_float2(c,s); return M; }
__device__ M2 mH(){ const float r=0.70710678118654752f; M2 M;
  M.m[0]=make_float2(r,0.f); M.m[1]=make_float2(r,0.f);
  M.m[2]=make_float2(r,0.f); M.m[3]=make_float2(-r,0.f); return M; }

// One vqc half: CNOT_{b->a} * (A2 kron B2) * CZ * (A1 kron B1)
__device__ M4 vqc_gate(const M2 A1, const M2 B1, const M2 A2, const M2 B2){
  M4 M = kron(A1,B1);
  #pragma unroll
  for (int c=0;c<4;c++){ M.m[12+c].x=-M.m[12+c].x; M.m[12+c].y=-M.m[12+c].y; } // CZ: negate row 3
  M4 T = mul4(kron(A2,B2), M);
  #pragma unroll
  for (int c=0;c<4;c++){ float2 tmp=T.m[4+c]; T.m[4+c]=T.m[12+c]; T.m[12+c]=tmp; } // CNOT(ctrl=b,tgt=a): swap rows 1,3
  return T;
}

// ---------- setup: compose fused gate matrices + ring permutation table ----------
__global__ void qm_setup(const float* __restrict__ params, float* __restrict__ wsf,
                         u16* __restrict__ ptab){
  int t = threadIdx.x;
  if (t < 5){
    int i = t;                       // pair (2i, 2i+1); a=2i (local bit1), b=2i+1 (local bit0)
    const float* p1 = params + 10 + i*12;   // v1[i]
    const float* p2 = params + 70 + i*12;   // v2[i]
    float ea = params[2*i], eb = params[2*i+1];
    // layer1 with H + RY(emb) folded in
    M2 A1 = mul2(mRZ(p1[4]), mul2(mRY(p1[2]), mul2(mRX(p1[0]), mul2(mRY(ea), mH()))));
    M2 B1 = mul2(mRX(p1[5]), mul2(mRZ(p1[3]), mul2(mRY(p1[1]), mul2(mRY(eb), mH()))));
    M2 A2 = mul2(mRX(p1[10]), mul2(mRY(p1[8]), mRZ(p1[6])));
    M2 B2 = mul2(mRY(p1[11]), mul2(mRZ(p1[9]), mRX(p1[7])));
    M4 G1 = vqc_gate(A1,B1,A2,B2);
    // layer2
    M2 A1b = mul2(mRZ(p2[4]), mul2(mRY(p2[2]), mRX(p2[0])));
    M2 B1b = mul2(mRX(p2[5]), mul2(mRZ(p2[3]), mRY(p2[1])));
    M2 A2b = mul2(mRX(p2[10]), mul2(mRY(p2[8]), mRZ(p2[6])));
    M2 B2b = mul2(mRY(p2[11]), mul2(mRZ(p2[9]), mRX(p2[7])));
    M4 G2 = vqc_gate(A1b,B1b,A2b,B2b);
    M4 G = mul4(G2, G1);
    float2* dst = (float2*)wsf + i*16;
    #pragma unroll
    for (int k=0;k<16;k++) dst[k]=G.m[k];
  } else if (t < 10){
    int i = t-5;                     // rot pair (2i, 2i+1)
    const float* sa = params + 130 + (2*i)*3;
    const float* sb = params + 130 + (2*i+1)*3;
    // rot(phi,theta,omega) = RZ(omega)*RY(theta)*RZ(phi)
    M2 Ra = mul2(mRZ(sa[2]), mul2(mRY(sa[1]), mRZ(sa[0])));
    M2 Rb = mul2(mRZ(sb[2]), mul2(mRY(sb[1]), mRZ(sb[0])));
    M4 R = kron(Ra, Rb);
    float2* dst = (float2*)wsf + 80 + i*16;
    #pragma unroll
    for (int k=0;k<16;k++) dst[k]=R.m[k];
  }
  // CNOT-ring permutation: CNOT(i,(i+1)%10) applied for i=0..9 in order.
  // wire w sits at state-index bit (9-w).
  for (int s=t; s<1024; s+=blockDim.x){
    int bb[10];
    #pragma unroll
    for (int w=0;w<10;w++) bb[w] = (s>>(9-w))&1;
    #pragma unroll
    for (int i=0;i<10;i++) bb[(i+1)%10] ^= bb[i];
    int sp=0;
    #pragma unroll
    for (int w=0;w<10;w++) sp |= bb[w]<<(9-w);
    ptab[s]=(u16)sp;
  }
}

// ---------- main: one block = one sample ----------
__global__ __launch_bounds__(256) void qm_sim(
    const float* __restrict__ x, const float* __restrict__ w_in,
    const float* __restrict__ b_in, const float* __restrict__ w_fc,
    const float* __restrict__ b_fc, const float* __restrict__ wsf,
    const u16* __restrict__ ptab, float* __restrict__ out)
{
  __shared__ float2 psi[1024];
  __shared__ float red[4];
  __shared__ float red2[4][20];
  __shared__ float tot[20];
  const int t = threadIdx.x;
  const int b = blockIdx.x;
  const int lane = t & 63, wid = t >> 6;

  // load x row (4 contiguous cols per thread), norm^2 partial, x-proj partials
  float4 xv = ((const float4*)x)[(size_t)b*256 + t];
  float n2 = xv.x*xv.x + xv.y*xv.y + xv.z*xv.z + xv.w*xv.w;
  float xp[10];
  #pragma unroll
  for (int q=0;q<10;q++){
    float4 wv = ((const float4*)w_in)[q*256 + t];
    xp[q] = xv.x*wv.x + xv.y*wv.y + xv.z*wv.z + xv.w*wv.w;
  }
  #pragma unroll
  for (int o=32;o;o>>=1) n2 += __shfl_xor(n2, o);
  if (lane==0) red[wid]=n2;
  __syncthreads();
  float rn = rsqrtf(red[0]+red[1]+red[2]+red[3]);
  psi[4*t+0]=make_float2(xv.x*rn,0.f);
  psi[4*t+1]=make_float2(xv.y*rn,0.f);
  psi[4*t+2]=make_float2(xv.z*rn,0.f);
  psi[4*t+3]=make_float2(xv.w*rn,0.f);
  __syncthreads();

  // 5 fused big gates (H+emb+layer1+layer2 per pair), pair j on bits (pb+1, pb), pb=8-2j
  #pragma unroll
  for (int j=0;j<5;j++){
    const int pb = 8-2*j;
    const int st = 1<<pb;
    const int m  = st-1;
    const float2* Gm = (const float2*)wsf + j*16;
    float2 g[16];
    #pragma unroll
    for (int k=0;k<16;k++) g[k]=Gm[k];
    int base = ((t & ~m) << 2) | (t & m);
    float2 a0=psi[base], a1=psi[base+st], a2=psi[base+2*st], a3=psi[base+3*st];
    #pragma unroll
    for (int L=0;L<4;L++){
      float2 r = cmul(g[4*L+0], a0);
      r = cmad(r, g[4*L+1], a1);
      r = cmad(r, g[4*L+2], a2);
      r = cmad(r, g[4*L+3], a3);
      psi[base + L*st] = r;
    }
    __syncthreads();
  }

  // CNOT ring #1 as a permutation scatter (read all, barrier, write all)
  float2 v0=psi[t], v1=psi[t+256], v2=psi[t+512], v3=psi[t+768];
  u16 pp0=ptab[t], pp1=ptab[t+256], pp2=ptab[t+512], pp3=ptab[t+768];
  __syncthreads();
  psi[pp0]=v0; psi[pp1]=v1; psi[pp2]=v2; psi[pp3]=v3;
  __syncthreads();

  // 5 fused rot-pair gates
  #pragma unroll
  for (int j=0;j<5;j++){
    const int pb = 8-2*j;
    const int st = 1<<pb;
    const int m  = st-1;
    const float2* Gm = (const float2*)wsf + 80 + j*16;
    float2 g[16];
    #pragma unroll
    for (int k=0;k<16;k++) g[k]=Gm[k];
    int base = ((t & ~m) << 2) | (t & m);
    float2 a0=psi[base], a1=psi[base+st], a2=psi[base+2*st], a3=psi[base+3*st];
    #pragma unroll
    for (int L=0;L<4;L++){
      float2 r = cmul(g[4*L+0], a0);
      r = cmad(r, g[4*L+1], a1);
      r = cmad(r, g[4*L+2], a2);
      r = cmad(r, g[4*L+3], a3);
      psi[base + L*st] = r;
    }
    __syncthreads();
  }

  // epilogue: q_out[q] = sum_s |psi[s]|^2 * sign(q, P(s))   (ring #2 folded into P lookup)
  float acc[10];
  #pragma unroll
  for (int q=0;q<10;q++) acc[q]=0.f;
  u16 pv0=pp0, pv1=pp1, pv2=pp2, pv3=pp3;   // same indices t+256k as loads below
  {
    float2 a;
    int sp;
    float p;
    a = psi[t];      p = a.x*a.x + a.y*a.y; sp = pv0;
    #pragma unroll
    for (int q=0;q<10;q++) acc[q] += ((sp>>(9-q))&1) ? -p : p;
    a = psi[t+256];  p = a.x*a.x + a.y*a.y; sp = pv1;
    #pragma unroll
    for (int q=0;q<10;q++) acc[q] += ((sp>>(9-q))&1) ? -p : p;
    a = psi[t+512];  p = a.x*a.x + a.y*a.y; sp = pv2;
    #pragma unroll
    for (int q=0;q<10;q++) acc[q] += ((sp>>(9-q))&1) ? -p : p;
    a = psi[t+768];  p = a.x*a.x + a.y*a.y; sp = pv3;
    #pragma unroll
    for (int q=0;q<10;q++) acc[q] += ((sp>>(9-q))&1) ? -p : p;
  }

  // block-reduce acc[10] and xp[10]
  #pragma unroll
  for (int q=0;q<10;q++){
    float v = acc[q];
    #pragma unroll
    for (int o=32;o;o>>=1) v += __shfl_xor(v, o);
    acc[q]=v;
    float w = xp[q];
    #pragma unroll
    for (int o=32;o;o>>=1) w += __shfl_xor(w, o);
    xp[q]=w;
  }
  if (lane==0){
    #pragma unroll
    for (int q=0;q<10;q++){ red2[wid][q]=acc[q]; red2[wid][10+q]=xp[q]; }
  }
  __syncthreads();
  if (t<20) tot[t] = red2[0][t]+red2[1][t]+red2[2][t]+red2[3][t];
  __syncthreads();
  if (t<10){
    float o = b_fc[t];
    #pragma unroll
    for (int q=0;q<10;q++) o += (tot[q] + tot[10+q] + b_in[q]) * w_fc[t*10+q];
    out[(size_t)b*10 + t] = o;
  }
}

extern "C" void kernel_launch(void* const* d_in, const int* in_sizes, int n_in,
                              void* d_out, int out_size, void* d_ws, size_t ws_size,
                              hipStream_t stream) {
  const float* x      = (const float*)d_in[0];
  const float* params = (const float*)d_in[1];
  const float* w_in   = (const float*)d_in[2];
  const float* b_in   = (const float*)d_in[3];
  const float* w_fc   = (const float*)d_in[4];
  const float* b_fc   = (const float*)d_in[5];
  float* out = (float*)d_out;

  float* wsf = (float*)d_ws;                         // 320 floats: 5 G mats + 5 R mats
  u16*   ptab = (u16*)((char*)d_ws + 1280);          // 1024 u16 permutation table

  int batch = in_sizes[0] >> 10;                     // 8192

  qm_setup<<<dim3(1), dim3(256), 0, stream>>>(params, wsf, ptab);
  qm_sim<<<dim3(batch), dim3(256), 0, stream>>>(x, w_in, b_in, w_fc, b_fc, wsf, ptab, out);
}